// Round 6
// baseline (73.794 us; speedup 1.0000x reference)
//
#include <hip/hip_runtime.h>

// FlowNetC fused: f1=conv3x3(x1,w), f2=conv3x3(x2,w),
// out[b,k,h,w] = mean_c f1[b,c,h,w]*f2[b,c,h+dy,w+dx], dy,dx in {-2,0,2}
// B=16,C=3,H=W=512,K=9. f32.
//
// R6: 64x32 tile / 512 threads (half the blocks, same 16 waves/CU),
// phase order f1 -> f2-direct-to-LDS-overlay (no f2 reg round trip),
// 1/3 folded into f1r. LDS 60.8KB: s_x2 (32.8KB) + overlay (28.7KB max).
// Weights via uniform cw[] reads -> SGPR s_loads. Width-16 global_load_lds
// staging, dwordx4 nontemporal stores, XCD-contiguous swizzle.

#define HH 512
#define WW 512
#define TSX 64
#define TSY 32
#define X2R 38              // TSY+6
#define X2S 72              // 70 cols padded to 72 (288B rows, 16B-aligned)
#define X1R 34              // TSY+2
#define X1S 68              // 66 cols padded to 68 (272B rows)
#define F2R 36              // TSY+4
#define F2S 68              // 68 cols exactly
#define NC2 (3*X2R*(X2S/4)) // 2052 16B chunks
#define NC1 (3*X1R*(X1S/4)) // 1734
#define NFU (F2R*(F2S/4))   // 612 f2 run-units

typedef const __attribute__((address_space(1))) void* gas_ptr;
typedef __attribute__((address_space(3))) void* las_ptr;
typedef float f32x4 __attribute__((ext_vector_type(4)));

__global__ __launch_bounds__(512)
void flownetc_fused_kernel(const float* __restrict__ x1,
                           const float* __restrict__ x2,
                           const float* __restrict__ cw,
                           float* __restrict__ out) {
  __shared__ __align__(16) float s_x2[3*X2R*X2S];        // 8208 w
  __shared__ __align__(16) float s_ov[3*F2R*F2S];        // 7344 w: x1 then f2

  const int tid = threadIdx.x;
  // XCD-contiguous swizzle: 2048 blocks / 8 XCDs = 256 contiguous each
  const int bid = blockIdx.x;
  const int f   = (bid & 7) * 256 + (bid >> 3);
  const int ox0 = (f & 7) * TSX;          // 8 x-tiles
  const int oy0 = ((f >> 3) & 15) * TSY;  // 16 y-tiles
  const int bi  = f >> 7;                 // 16 batches

  const float* x2b = x2 + (size_t)bi * 3 * HH * WW;
  const float* x1b = x1 + (size_t)bi * 3 * HH * WW;

  // ---- stage x2 [3][38][72] origin (oy0-3, ox0-3), 16B chunks ----
  #pragma unroll
  for (int it = 0; it < 5; ++it) {
    const int q = it * 512 + tid;
    if (q < NC2) {
      const int colq = q % (X2S / 4);
      const int rp   = q / (X2S / 4);
      const int r    = rp % X2R;
      const int c    = rp / X2R;
      const int gy   = oy0 - 3 + r;
      const int gx0  = ox0 - 3 + colq * 4;
      const float* src = x2b + (size_t)(c * HH + gy) * WW + gx0;
      if ((unsigned)gy < HH && (unsigned)gx0 <= (WW - 4)) {
        __builtin_amdgcn_global_load_lds((gas_ptr)src,
            (las_ptr)(s_x2 + ((q & ~63) << 2)), 16, 0, 0);
      } else {
        const bool rowok = (unsigned)gy < HH;
        float4 v;
        v.x = (rowok && (unsigned)(gx0 + 0) < WW) ? src[0] : 0.f;
        v.y = (rowok && (unsigned)(gx0 + 1) < WW) ? src[1] : 0.f;
        v.z = (rowok && (unsigned)(gx0 + 2) < WW) ? src[2] : 0.f;
        v.w = (rowok && (unsigned)(gx0 + 3) < WW) ? src[3] : 0.f;
        *reinterpret_cast<float4*>(&s_x2[q * 4]) = v;
      }
    }
  }
  // ---- stage x1 [3][34][68] origin (oy0-1, ox0-1) into s_ov ----
  #pragma unroll
  for (int it = 0; it < 4; ++it) {
    const int q = it * 512 + tid;
    if (q < NC1) {
      const int colq = q % (X1S / 4);
      const int rp   = q / (X1S / 4);
      const int r    = rp % X1R;
      const int c    = rp / X1R;
      const int gy   = oy0 - 1 + r;
      const int gx0  = ox0 - 1 + colq * 4;
      const float* src = x1b + (size_t)(c * HH + gy) * WW + gx0;
      if ((unsigned)gy < HH && (unsigned)gx0 <= (WW - 4)) {
        __builtin_amdgcn_global_load_lds((gas_ptr)src,
            (las_ptr)(s_ov + ((q & ~63) << 2)), 16, 0, 0);
      } else {
        const bool rowok = (unsigned)gy < HH;
        float4 v;
        v.x = (rowok && (unsigned)(gx0 + 0) < WW) ? src[0] : 0.f;
        v.y = (rowok && (unsigned)(gx0 + 1) < WW) ? src[1] : 0.f;
        v.z = (rowok && (unsigned)(gx0 + 2) < WW) ? src[2] : 0.f;
        v.w = (rowok && (unsigned)(gx0 + 3) < WW) ? src[3] : 0.f;
        *reinterpret_cast<float4*>(&s_ov[q * 4]) = v;
      }
    }
  }
  __syncthreads();   // staging complete

  // ---- phase B: f1 (regs) from s_ov-as-x1; exactly 512 units ----
  const int py  = tid >> 4;          // 0..31
  const int px0 = (tid & 15) << 2;   // 0..60
  float f1r[3][4] = {};
  #pragma unroll
  for (int ci = 0; ci < 3; ++ci) {
    float win[3][6];
    #pragma unroll
    for (int ky = 0; ky < 3; ++ky) {
      const float* base = &s_ov[(ci * X1R + py + ky) * X1S + px0];
      const float4 a  = *reinterpret_cast<const float4*>(base);
      const float2 b2 = *reinterpret_cast<const float2*>(base + 4);
      win[ky][0] = a.x; win[ky][1] = a.y; win[ky][2] = a.z; win[ky][3] = a.w;
      win[ky][4] = b2.x; win[ky][5] = b2.y;
    }
    #pragma unroll
    for (int co = 0; co < 3; ++co)
      #pragma unroll
      for (int ky = 0; ky < 3; ++ky)
        #pragma unroll
        for (int kx = 0; kx < 3; ++kx) {
          const float w = cw[((co * 3 + ci) * 3 + ky) * 3 + kx]; // uniform -> SGPR
          #pragma unroll
          for (int j = 0; j < 4; ++j)
            f1r[co][j] += w * win[ky][j + kx];
        }
  }
  #pragma unroll
  for (int co = 0; co < 3; ++co)
    #pragma unroll
    for (int j = 0; j < 4; ++j)
      f1r[co][j] *= (1.f / 3.f);     // fold mean-divisor once
  __syncthreads();   // x1 data in s_ov is dead now

  // ---- phase C: f2 directly into s_ov overlay; 612 units ----
  #pragma unroll
  for (int half = 0; half < 2; ++half) {
    const int u = half * 512 + tid;
    if (u < NFU) {
      const int col0 = (u % (F2S / 4)) * 4;
      const int r    = u / (F2S / 4);
      float acc[3][4] = {};
      #pragma unroll
      for (int ci = 0; ci < 3; ++ci) {
        float win[3][6];
        #pragma unroll
        for (int ky = 0; ky < 3; ++ky) {
          const float* base = &s_x2[(ci * X2R + r + ky) * X2S + col0];
          const float4 a  = *reinterpret_cast<const float4*>(base);
          const float2 b2 = *reinterpret_cast<const float2*>(base + 4);
          win[ky][0] = a.x; win[ky][1] = a.y; win[ky][2] = a.z; win[ky][3] = a.w;
          win[ky][4] = b2.x; win[ky][5] = b2.y;
        }
        #pragma unroll
        for (int co = 0; co < 3; ++co)
          #pragma unroll
          for (int ky = 0; ky < 3; ++ky)
            #pragma unroll
            for (int kx = 0; kx < 3; ++kx) {
              const float w = cw[((co * 3 + ci) * 3 + ky) * 3 + kx];
              #pragma unroll
              for (int j = 0; j < 4; ++j)
                acc[co][j] += w * win[ky][j + kx];
            }
      }
      // correlation zero-pads f2: zero outside the image
      const int gy = oy0 - 2 + r;
      #pragma unroll
      for (int j = 0; j < 4; ++j) {
        const int gx = ox0 - 2 + col0 + j;
        if (!((unsigned)gy < HH && (unsigned)gx < WW)) {
          acc[0][j] = 0.f; acc[1][j] = 0.f; acc[2][j] = 0.f;
        }
      }
      #pragma unroll
      for (int co = 0; co < 3; ++co)
        *reinterpret_cast<float4*>(&s_ov[(co * F2R + r) * F2S + col0]) =
            make_float4(acc[co][0], acc[co][1], acc[co][2], acc[co][3]);
    }
  }
  __syncthreads();   // f2 tile ready

  // ---- correlation + nontemporal dwordx4 stores ----
  float* outp = out + ((size_t)bi * 9 * HH + (oy0 + py)) * WW + ox0 + px0;
  #pragma unroll
  for (int dyi = 0; dyi < 3; ++dyi) {
    float rv[3][8];
    #pragma unroll
    for (int c = 0; c < 3; ++c) {
      const float* base = &s_ov[(c * F2R + py + dyi * 2) * F2S + px0];
      const float4 a = *reinterpret_cast<const float4*>(base);
      const float4 b = *reinterpret_cast<const float4*>(base + 4);
      rv[c][0] = a.x; rv[c][1] = a.y; rv[c][2] = a.z; rv[c][3] = a.w;
      rv[c][4] = b.x; rv[c][5] = b.y; rv[c][6] = b.z; rv[c][7] = b.w;
    }
    #pragma unroll
    for (int dxi = 0; dxi < 3; ++dxi) {
      const int s = dxi * 2;
      f32x4 o;
      o.x = f1r[0][0]*rv[0][s+0] + f1r[1][0]*rv[1][s+0] + f1r[2][0]*rv[2][s+0];
      o.y = f1r[0][1]*rv[0][s+1] + f1r[1][1]*rv[1][s+1] + f1r[2][1]*rv[2][s+1];
      o.z = f1r[0][2]*rv[0][s+2] + f1r[1][2]*rv[1][s+2] + f1r[2][2]*rv[2][s+2];
      o.w = f1r[0][3]*rv[0][s+3] + f1r[1][3]*rv[1][s+3] + f1r[2][3]*rv[2][s+3];
      __builtin_nontemporal_store(o,
          reinterpret_cast<f32x4*>(outp + (size_t)(dyi * 3 + dxi) * HH * WW));
    }
  }
}

extern "C" void kernel_launch(void* const* d_in, const int* in_sizes, int n_in,
                              void* d_out, int out_size, void* d_ws, size_t ws_size,
                              hipStream_t stream) {
  const float* x1 = (const float*)d_in[0];
  const float* x2 = (const float*)d_in[1];
  const float* cw = (const float*)d_in[2];
  float* out = (float*)d_out;

  flownetc_fused_kernel<<<dim3(2048), 512, 0, stream>>>(x1, x2, cw, out);
}